// Round 14
// baseline (327.126 us; speedup 1.0000x reference)
//
#include <hip/hip_runtime.h>
#include <hip/hip_bf16.h>

typedef unsigned short u16;
typedef __attribute__((ext_vector_type(8))) short short8;
typedef __attribute__((ext_vector_type(4))) float floatx4;

#define TOKENS 8192
#define KDIM   2048
#define NFEAT  8192
#define R_     4
#define N1_    2048
#define M1_    1024

#define BM 256
#define BN 256
#define BK 64
#define NITER (KDIM / (2 * BK))   // 16 iterations, 2 K-tiles each

__device__ __forceinline__ u16 f2bf(float f) {
  union { float f; unsigned u; } v; v.f = f;
  unsigned r = v.u + 0x7fffu + ((v.u >> 16) & 1u);  // RNE
  return (u16)(r >> 16);
}

// ---- P0: invert permutation (tiny, once) ----
__global__ void k_invert_perm(const int* __restrict__ p_inv, int* __restrict__ pf) {
  int i = blockIdx.x * 256 + threadIdx.x;
  if (i < KDIM) pf[p_inv[i]] = i;
}

// ---- P1: fused prep: blocks [0,8192) cvt x->bf16 (32B/thread);
//          blocks [8192,16384) build Wf (pf read from global, L2-hot) ----
#define CVT_BLOCKS 8192
struct u16x4 { u16 a, b, c, d; };
__global__ void k_prep(const float4* __restrict__ x4, u16x4* __restrict__ xb,
                       const float* __restrict__ A, const float* __restrict__ Bm,
                       const int* __restrict__ pf, const int* __restrict__ q,
                       u16* __restrict__ Wf) {
  int bid = blockIdx.x;
  if (bid < CVT_BLOCKS) {
    int i = (bid * 256 + threadIdx.x) * 2;
#pragma unroll
    for (int t = 0; t < 2; ++t) {
      float4 v = x4[i + t];
      u16x4 o; o.a = f2bf(v.x); o.b = f2bf(v.y); o.c = f2bf(v.z); o.d = f2bf(v.w);
      xb[i + t] = o;
    }
  } else {
    int f = bid - CVT_BLOCKS;
    int k0 = threadIdx.x * 8;
    int qf = q[f];
    int n = qf >> 2, jq = qf & 3;
    const float* An = A + (size_t)n * M1_;
    float bc[8];
#pragma unroll
    for (int r = 0; r < R_; ++r) {
      bc[r * 2 + 0] = Bm[r * 8 + 0 * 4 + jq];
      bc[r * 2 + 1] = Bm[r * 8 + 1 * 4 + jq];
    }
    int4 c0 = *(const int4*)(pf + k0);
    int4 c1 = *(const int4*)(pf + k0 + 4);
    int cs[8] = {c0.x, c0.y, c0.z, c0.w, c1.x, c1.y, c1.z, c1.w};
    u16 w[8];
#pragma unroll
    for (int i = 0; i < 8; ++i) {
      int m1 = cs[i] >> 1, m2 = cs[i] & 1;
      float acc = 0.f;
#pragma unroll
      for (int r = 0; r < R_; ++r)
        acc += An[(size_t)r * (N1_ * M1_) + m1] * bc[r * 2 + m2];
      w[i] = f2bf(acc);
    }
    *(short8*)(Wf + (size_t)f * KDIM + k0) = *(const short8*)w;
  }
}

// ---- GEMM: R8 schedule; MM reordered kk-outer (independent MFMA stream);
//      nontemporal C stores. Cross-round-reuse mapping (R13).
#define GLD16(gp, lp) __builtin_amdgcn_global_load_lds( \
    (const __attribute__((address_space(1))) void*)(gp), \
    (__attribute__((address_space(3))) void*)(lp), 16, 0, 0)

#define FENCE asm volatile("" ::: "memory")
#define BAR   do { FENCE; __builtin_amdgcn_s_barrier(); FENCE; } while (0)
#define LGKM0 asm volatile("s_waitcnt lgkmcnt(0)" ::: "memory")
#define VMCNT(n) asm volatile("s_waitcnt vmcnt(" #n ")" ::: "memory")

__global__ __launch_bounds__(512, 2) void k_gemm(
    const u16* __restrict__ X, const u16* __restrict__ W,
    const float* __restrict__ bias, float* __restrict__ out) {
  // slot (64KB x2): A-half0 16K | A-half1 16K | B-half0 16K | B-half1 16K
  __shared__ __align__(16) char lds[2 * 65536];

  // cross-round-reuse mapping: tM depends on round u; tN fixed per XCD
  int bid = blockIdx.x;
  int xcd = bid & 7;
  int loc = bid >> 3;
  int u = loc >> 5, v = loc & 31;
  int tM = u * 8 + (v >> 2);         // [0,32)
  int tN = xcd * 4 + (v & 3);        // [0,32)
  int rowBase = tM * BM, colBase = tN * BN;

  int tid = threadIdx.x, lane = tid & 63, wave = tid >> 6;
  int wm = wave >> 2;                // 0..1 : rows [wm*128, +128)
  int wn = wave & 3;                 // 0..3 : cols [wn*64, +64)

  // staging: pre-swizzled global source, linear LDS dest (both-sides involution)
  int srow = tid >> 3;
  int scol = ((tid & 7) ^ (srow & 7)) * 8;
  const u16* Asrc = X + (size_t)(rowBase + srow) * KDIM + scol;
  const u16* Bsrc = W + (size_t)(colBase + srow) * KDIM + scol;

  auto SA = [&](int slot, int half, int kt) {
#pragma unroll
    for (int jj = 0; jj < 2; ++jj)
      GLD16(Asrc + (size_t)(half * 128 + jj * 64) * KDIM + kt * 64,
            &lds[slot * 65536 + half * 16384 + jj * 8192 + tid * 16]);
  };
  auto SB = [&](int slot, int half, int kt) {
#pragma unroll
    for (int jj = 0; jj < 2; ++jj)
      GLD16(Bsrc + (size_t)(half * 128 + jj * 64) * KDIM + kt * 64,
            &lds[slot * 65536 + 32768 + half * 16384 + jj * 8192 + tid * 16]);
  };

  // fragment reads: row*128 + ((kk*4 + lane>>4) ^ (lane&7))*16
  int l15 = lane & 15, lhi = lane >> 4, l7 = lane & 7;
  int x0 = (lhi ^ l7) * 16;
  int x1 = ((4 + lhi) ^ l7) * 16;
  int abase = wm * 16384 + l15 * 128;
  int bbase = 32768 + (wn >> 1) * 16384 + ((wn & 1) * 64 + l15) * 128;

  auto RA = [&](int slot, int m, int kk) -> short8 {
    return *(const short8*)&lds[slot * 65536 + abase + m * 2048 + (kk ? x1 : x0)];
  };
  auto RB = [&](int slot, int n, int kk) -> short8 {
    return *(const short8*)&lds[slot * 65536 + bbase + n * 2048 + (kk ? x1 : x0)];
  };

  floatx4 acc[8][4] = {};
  short8 a[4][2], a2[4][2], b[2][2], b2[2][2];

  auto RDa = [&](int slot) {
#pragma unroll
    for (int m = 0; m < 4; ++m) { a[m][0] = RA(slot, m, 0); a[m][1] = RA(slot, m, 1); }
  };
  auto RDa2 = [&](int slot) {
#pragma unroll
    for (int m = 0; m < 4; ++m) { a2[m][0] = RA(slot, 4 + m, 0); a2[m][1] = RA(slot, 4 + m, 1); }
  };
  auto RDb = [&](int slot) {
#pragma unroll
    for (int n = 0; n < 2; ++n) { b[n][0] = RB(slot, n, 0); b[n][1] = RB(slot, n, 1); }
  };
  auto RDb2 = [&](int slot) {
#pragma unroll
    for (int n = 0; n < 2; ++n) { b2[n][0] = RB(slot, 2 + n, 0); b2[n][1] = RB(slot, 2 + n, 1); }
  };

  // kk-outer: 8 independent MFMAs between dependent uses of the same acc;
  // per-acc order still k0 -> k1 (bit-identical accumulation).
  auto MM = [&](short8 (&Af)[4][2], short8 (&Bf)[2][2], int mo, int no) {
    __builtin_amdgcn_s_setprio(1);
#pragma unroll
    for (int kk = 0; kk < 2; ++kk)
#pragma unroll
      for (int m = 0; m < 4; ++m)
#pragma unroll
        for (int n = 0; n < 2; ++n)
          acc[mo + m][no + n] = __builtin_amdgcn_mfma_f32_16x16x32_bf16(
              Af[m][kk], Bf[n][kk], acc[mo + m][no + n], 0, 0, 0);
    __builtin_amdgcn_s_setprio(0);
  };

  // ---- prologue: slot0 = tile0 (8 loads), slot1 = tile1 (8 loads, in flight)
  SA(0, 0, 0); SA(0, 1, 0); SB(0, 0, 0); SB(0, 1, 0);
  SA(1, 0, 1); SA(1, 1, 1); SB(1, 0, 1); SB(1, 1, 1);
  VMCNT(8);                 // slot0's 8 landed; slot1's 8 in flight
  BAR;
  RDa(0); RDb(0);           // q00 fragments for ph1

  for (int it = 0; it < NITER - 1; ++it) {
    int t0 = 2 * it;
    // ph1: MFMA q00(s0); read a2(s0)                      [no barrier]
    LGKM0; RDa2(0);
    MM(a, b, 0, 0);
    FENCE;
    // ph2: MFMA q10; read b2(s0)
    LGKM0; RDb2(0);
    MM(a2, b, 4, 0);
    BAR;
    // ph3: MFMA q11; stage SA(0,*,t0+2); publish slot1 (flights 4,4,3,3)
    LGKM0;
    SA(0, 0, t0 + 2); SA(0, 1, t0 + 2);
    MM(a2, b2, 4, 2);
    VMCNT(4);
    BAR;
    // ph4: MFMA q01; stage SB(0,*,t0+2); read a,b (s1)    [no barrier]
    LGKM0;
    SB(0, 0, t0 + 2); SB(0, 1, t0 + 2);
    MM(a, b2, 0, 2);
    RDa(1); RDb(1);
    FENCE;
    // ph5: MFMA q00(s1); read a2(s1)                      [no barrier]
    LGKM0; RDa2(1);
    MM(a, b, 0, 0);
    FENCE;
    // ph6: MFMA q10; read b2(s1)
    LGKM0; RDb2(1);
    MM(a2, b, 4, 0);
    BAR;
    // ph7: MFMA q11; stage SA(1,*,t0+3); publish slot0(t0+2)
    LGKM0;
    SA(1, 0, t0 + 3); SA(1, 1, t0 + 3);
    MM(a2, b2, 4, 2);
    VMCNT(4);
    BAR;
    // ph8: MFMA q01; stage SB(1,*,t0+3); read a,b (s0)    [no barrier]
    LGKM0;
    SB(1, 0, t0 + 3); SB(1, 1, t0 + 3);
    MM(a, b2, 0, 2);
    RDa(0); RDb(0);
    FENCE;
  }

  // ---- tail iteration (t0=30, t1=31): no staging
  {
    LGKM0; RDa2(0); MM(a, b, 0, 0); FENCE;
    LGKM0; RDb2(0); MM(a2, b, 4, 0); BAR;
    LGKM0; MM(a2, b2, 4, 2); VMCNT(0); BAR;   // publish slot1 (drain all)
    LGKM0; MM(a, b2, 0, 2); RDa(1); RDb(1); FENCE;
    LGKM0; RDa2(1); MM(a, b, 0, 0); FENCE;
    LGKM0; RDb2(1); MM(a2, b, 4, 0); FENCE;
    LGKM0; MM(a2, b2, 4, 2); FENCE;
    LGKM0; MM(a, b2, 0, 2);
  }

  // ---- epilogue: C = acc + bias; nontemporal stores (no write-allocate RMW)
  float bv[4];
#pragma unroll
  for (int n = 0; n < 4; ++n)
    bv[n] = bias[colBase + wn * 64 + n * 16 + l15];
#pragma unroll
  for (int m = 0; m < 8; ++m) {
    int r0 = wm * 128 + m * 16 + (lhi << 2);
#pragma unroll
    for (int n = 0; n < 4; ++n) {
      size_t basep = (size_t)(rowBase + r0) * NFEAT + colBase + wn * 64 + n * 16 + l15;
#pragma unroll
      for (int reg = 0; reg < 4; ++reg)
        __builtin_nontemporal_store(acc[m][n][reg] + bv[n], &out[basep + (size_t)reg * NFEAT]);
    }
  }
}

extern "C" void kernel_launch(void* const* d_in, const int* in_sizes, int n_in,
                              void* d_out, int out_size, void* d_ws, size_t ws_size,
                              hipStream_t stream) {
  const float* x     = (const float*)d_in[0];
  const float* A     = (const float*)d_in[1];
  const float* Bm    = (const float*)d_in[2];
  const float* bias  = (const float*)d_in[3];
  const int*   p_inv = (const int*)d_in[4];
  const int*   q     = (const int*)d_in[5];
  float* out = (float*)d_out;

  u16* Xb = (u16*)d_ws;
  u16* Wf = (u16*)((char*)d_ws + (size_t)TOKENS * KDIM * 2);
  int* pf = (int*)((char*)d_ws + (size_t)TOKENS * KDIM * 2 * 2);

  k_invert_perm<<<(KDIM + 255) / 256, 256, 0, stream>>>(p_inv, pf);
  k_prep<<<CVT_BLOCKS + NFEAT, 256, 0, stream>>>((const float4*)x, (u16x4*)Xb, A, Bm, pf, q, Wf);
  k_gemm<<<(TOKENS / BM) * (NFEAT / BN), 512, 0, stream>>>(Xb, Wf, bias, out);
}

// Round 15
// 267.409 us; speedup vs baseline: 1.2233x; 1.2233x over previous
//
#include <hip/hip_runtime.h>
#include <hip/hip_bf16.h>

typedef unsigned short u16;
typedef __attribute__((ext_vector_type(8))) short short8;
typedef __attribute__((ext_vector_type(4))) float floatx4;

#define TOKENS 8192
#define KDIM   2048
#define NFEAT  8192
#define R_     4
#define N1_    2048
#define M1_    1024

#define BM 256
#define BN 256
#define BK 64
#define NITER (KDIM / (2 * BK))   // 16 iterations, 2 K-tiles each

__device__ __forceinline__ u16 f2bf(float f) {
  union { float f; unsigned u; } v; v.f = f;
  unsigned r = v.u + 0x7fffu + ((v.u >> 16) & 1u);  // RNE
  return (u16)(r >> 16);
}

// ---- P1: fused prep, 16384 blocks.
//  blocks [0,8192): Xp[t][c] = bf16(x[t][p_inv[c]]) — permute folded into cvt
//                   (gathers stay within one 8KB L1-resident x-row).
//  blocks [8192,16384): V[f][c] = sum_r A[r, q[f]>>2, c>>1] * B[r, c&1, q[f]&3]
//                   — c linear: pure float4 loads, zero gathers.
__global__ void k_prep(const float* __restrict__ x, u16* __restrict__ xb,
                       const float* __restrict__ A, const float* __restrict__ Bm,
                       const int* __restrict__ p_inv, const int* __restrict__ q,
                       u16* __restrict__ Wf) {
  int bid = blockIdx.x;
  int c0 = threadIdx.x * 8;
  if (bid < TOKENS) {
    const float* xrow = x + (size_t)bid * KDIM;
    int4 i0 = *(const int4*)(p_inv + c0);
    int4 i1 = *(const int4*)(p_inv + c0 + 4);
    int idx[8] = {i0.x, i0.y, i0.z, i0.w, i1.x, i1.y, i1.z, i1.w};
    u16 w[8];
#pragma unroll
    for (int i = 0; i < 8; ++i) w[i] = f2bf(xrow[idx[i]]);
    *(short8*)(xb + (size_t)bid * KDIM + c0) = *(const short8*)w;
  } else {
    int f = bid - TOKENS;
    int qf = q[f];
    int n = qf >> 2, jq = qf & 3;
    const float* An = A + (size_t)n * M1_;
    float bc[8];
#pragma unroll
    for (int r = 0; r < R_; ++r) {
      bc[r * 2 + 0] = Bm[r * 8 + 0 * 4 + jq];
      bc[r * 2 + 1] = Bm[r * 8 + 1 * 4 + jq];
    }
    float4 a4[4];
#pragma unroll
    for (int r = 0; r < R_; ++r)
      a4[r] = *(const float4*)(An + (size_t)r * (N1_ * M1_) + (c0 >> 1));
    u16 w[8];
#pragma unroll
    for (int i = 0; i < 8; ++i) {
      int mo = i >> 1, m2 = i & 1;
      float acc = 0.f;
#pragma unroll
      for (int r = 0; r < R_; ++r)
        acc += ((const float*)&a4[r])[mo] * bc[r * 2 + m2];
      w[i] = f2bf(acc);
    }
    *(short8*)(Wf + (size_t)f * KDIM + c0) = *(const short8*)w;
  }
}

// ---- GEMM: R13 build verbatim (proven 236.6 us): R8 8-phase / 4-barrier
//      schedule, VMCNT(4) publishes at ph3/ph7, XOR-swizzled LDS,
//      cross-round-reuse mapping, original MM order, normal stores.
#define GLD16(gp, lp) __builtin_amdgcn_global_load_lds( \
    (const __attribute__((address_space(1))) void*)(gp), \
    (__attribute__((address_space(3))) void*)(lp), 16, 0, 0)

#define FENCE asm volatile("" ::: "memory")
#define BAR   do { FENCE; __builtin_amdgcn_s_barrier(); FENCE; } while (0)
#define LGKM0 asm volatile("s_waitcnt lgkmcnt(0)" ::: "memory")
#define VMCNT(n) asm volatile("s_waitcnt vmcnt(" #n ")" ::: "memory")

__global__ __launch_bounds__(512, 2) void k_gemm(
    const u16* __restrict__ X, const u16* __restrict__ W,
    const float* __restrict__ bias, float* __restrict__ out) {
  // slot (64KB x2): A-half0 16K | A-half1 16K | B-half0 16K | B-half1 16K
  __shared__ __align__(16) char lds[2 * 65536];

  // cross-round-reuse mapping: tM depends on round u; tN fixed per XCD
  int bid = blockIdx.x;
  int xcd = bid & 7;
  int loc = bid >> 3;
  int u = loc >> 5, v = loc & 31;
  int tM = u * 8 + (v >> 2);         // [0,32)
  int tN = xcd * 4 + (v & 3);        // [0,32)
  int rowBase = tM * BM, colBase = tN * BN;

  int tid = threadIdx.x, lane = tid & 63, wave = tid >> 6;
  int wm = wave >> 2;                // 0..1 : rows [wm*128, +128)
  int wn = wave & 3;                 // 0..3 : cols [wn*64, +64)

  // staging: pre-swizzled global source, linear LDS dest (both-sides involution)
  int srow = tid >> 3;
  int scol = ((tid & 7) ^ (srow & 7)) * 8;
  const u16* Asrc = X + (size_t)(rowBase + srow) * KDIM + scol;
  const u16* Bsrc = W + (size_t)(colBase + srow) * KDIM + scol;

  auto SA = [&](int slot, int half, int kt) {
#pragma unroll
    for (int jj = 0; jj < 2; ++jj)
      GLD16(Asrc + (size_t)(half * 128 + jj * 64) * KDIM + kt * 64,
            &lds[slot * 65536 + half * 16384 + jj * 8192 + tid * 16]);
  };
  auto SB = [&](int slot, int half, int kt) {
#pragma unroll
    for (int jj = 0; jj < 2; ++jj)
      GLD16(Bsrc + (size_t)(half * 128 + jj * 64) * KDIM + kt * 64,
            &lds[slot * 65536 + 32768 + half * 16384 + jj * 8192 + tid * 16]);
  };

  // fragment reads: row*128 + ((kk*4 + lane>>4) ^ (lane&7))*16
  int l15 = lane & 15, lhi = lane >> 4, l7 = lane & 7;
  int x0 = (lhi ^ l7) * 16;
  int x1 = ((4 + lhi) ^ l7) * 16;
  int abase = wm * 16384 + l15 * 128;
  int bbase = 32768 + (wn >> 1) * 16384 + ((wn & 1) * 64 + l15) * 128;

  auto RA = [&](int slot, int m, int kk) -> short8 {
    return *(const short8*)&lds[slot * 65536 + abase + m * 2048 + (kk ? x1 : x0)];
  };
  auto RB = [&](int slot, int n, int kk) -> short8 {
    return *(const short8*)&lds[slot * 65536 + bbase + n * 2048 + (kk ? x1 : x0)];
  };

  floatx4 acc[8][4] = {};
  short8 a[4][2], a2[4][2], b[2][2], b2[2][2];

  auto RDa = [&](int slot) {
#pragma unroll
    for (int m = 0; m < 4; ++m) { a[m][0] = RA(slot, m, 0); a[m][1] = RA(slot, m, 1); }
  };
  auto RDa2 = [&](int slot) {
#pragma unroll
    for (int m = 0; m < 4; ++m) { a2[m][0] = RA(slot, 4 + m, 0); a2[m][1] = RA(slot, 4 + m, 1); }
  };
  auto RDb = [&](int slot) {
#pragma unroll
    for (int n = 0; n < 2; ++n) { b[n][0] = RB(slot, n, 0); b[n][1] = RB(slot, n, 1); }
  };
  auto RDb2 = [&](int slot) {
#pragma unroll
    for (int n = 0; n < 2; ++n) { b2[n][0] = RB(slot, 2 + n, 0); b2[n][1] = RB(slot, 2 + n, 1); }
  };

  auto MM = [&](short8 (&Af)[4][2], short8 (&Bf)[2][2], int mo, int no) {
    __builtin_amdgcn_s_setprio(1);
#pragma unroll
    for (int m = 0; m < 4; ++m)
#pragma unroll
      for (int n = 0; n < 2; ++n) {
        acc[mo + m][no + n] = __builtin_amdgcn_mfma_f32_16x16x32_bf16(Af[m][0], Bf[n][0], acc[mo + m][no + n], 0, 0, 0);
        acc[mo + m][no + n] = __builtin_amdgcn_mfma_f32_16x16x32_bf16(Af[m][1], Bf[n][1], acc[mo + m][no + n], 0, 0, 0);
      }
    __builtin_amdgcn_s_setprio(0);
  };

  // ---- prologue: slot0 = tile0 (8 loads), slot1 = tile1 (8 loads, in flight)
  SA(0, 0, 0); SA(0, 1, 0); SB(0, 0, 0); SB(0, 1, 0);
  SA(1, 0, 1); SA(1, 1, 1); SB(1, 0, 1); SB(1, 1, 1);
  VMCNT(8);                 // slot0's 8 landed; slot1's 8 in flight
  BAR;
  RDa(0); RDb(0);           // q00 fragments for ph1

  for (int it = 0; it < NITER - 1; ++it) {
    int t0 = 2 * it;
    // ph1: MFMA q00(s0); read a2(s0)                      [no barrier]
    LGKM0; RDa2(0);
    MM(a, b, 0, 0);
    FENCE;
    // ph2: MFMA q10; read b2(s0)
    LGKM0; RDb2(0);
    MM(a2, b, 4, 0);
    BAR;
    // ph3: MFMA q11; stage SA(0,*,t0+2); publish slot1 (flights 4,4,3,3)
    LGKM0;
    SA(0, 0, t0 + 2); SA(0, 1, t0 + 2);
    MM(a2, b2, 4, 2);
    VMCNT(4);
    BAR;
    // ph4: MFMA q01; stage SB(0,*,t0+2); read a,b (s1)    [no barrier]
    LGKM0;
    SB(0, 0, t0 + 2); SB(0, 1, t0 + 2);
    MM(a, b2, 0, 2);
    RDa(1); RDb(1);
    FENCE;
    // ph5: MFMA q00(s1); read a2(s1)                      [no barrier]
    LGKM0; RDa2(1);
    MM(a, b, 0, 0);
    FENCE;
    // ph6: MFMA q10; read b2(s1)
    LGKM0; RDb2(1);
    MM(a2, b, 4, 0);
    BAR;
    // ph7: MFMA q11; stage SA(1,*,t0+3); publish slot0(t0+2)
    LGKM0;
    SA(1, 0, t0 + 3); SA(1, 1, t0 + 3);
    MM(a2, b2, 4, 2);
    VMCNT(4);
    BAR;
    // ph8: MFMA q01; stage SB(1,*,t0+3); read a,b (s0)    [no barrier]
    LGKM0;
    SB(1, 0, t0 + 3); SB(1, 1, t0 + 3);
    MM(a, b2, 0, 2);
    RDa(0); RDb(0);
    FENCE;
  }

  // ---- tail iteration (t0=30, t1=31): no staging
  {
    LGKM0; RDa2(0); MM(a, b, 0, 0); FENCE;
    LGKM0; RDb2(0); MM(a2, b, 4, 0); BAR;
    LGKM0; MM(a2, b2, 4, 2); VMCNT(0); BAR;   // publish slot1 (drain all)
    LGKM0; MM(a, b2, 0, 2); RDa(1); RDb(1); FENCE;
    LGKM0; RDa2(1); MM(a, b, 0, 0); FENCE;
    LGKM0; RDb2(1); MM(a2, b, 4, 0); FENCE;
    LGKM0; MM(a2, b2, 4, 2); FENCE;
    LGKM0; MM(a, b2, 0, 2);
  }

  // ---- epilogue: C = acc + bias; C/D layout col=lane&15, row=(lane>>4)*4+reg
  float bv[4];
#pragma unroll
  for (int n = 0; n < 4; ++n)
    bv[n] = bias[colBase + wn * 64 + n * 16 + l15];
#pragma unroll
  for (int m = 0; m < 8; ++m) {
    int r0 = wm * 128 + m * 16 + (lhi << 2);
#pragma unroll
    for (int n = 0; n < 4; ++n) {
      size_t basep = (size_t)(rowBase + r0) * NFEAT + colBase + wn * 64 + n * 16 + l15;
#pragma unroll
      for (int reg = 0; reg < 4; ++reg)
        out[basep + (size_t)reg * NFEAT] = acc[m][n][reg] + bv[n];
    }
  }
}

extern "C" void kernel_launch(void* const* d_in, const int* in_sizes, int n_in,
                              void* d_out, int out_size, void* d_ws, size_t ws_size,
                              hipStream_t stream) {
  const float* x     = (const float*)d_in[0];
  const float* A     = (const float*)d_in[1];
  const float* Bm    = (const float*)d_in[2];
  const float* bias  = (const float*)d_in[3];
  const int*   p_inv = (const int*)d_in[4];
  const int*   q     = (const int*)d_in[5];
  float* out = (float*)d_out;

  u16* Xb = (u16*)d_ws;                                          // Xp (permuted, bf16)
  u16* Wf = (u16*)((char*)d_ws + (size_t)TOKENS * KDIM * 2);     // V (c-space, bf16)

  k_prep<<<TOKENS + NFEAT, 256, 0, stream>>>(x, Xb, A, Bm, p_inv, q, Wf);
  k_gemm<<<(TOKENS / BM) * (NFEAT / BN), 512, 0, stream>>>(Xb, Wf, bias, out);
}